// Round 12
// baseline (97.216 us; speedup 1.0000x reference)
//
#include <hip/hip_runtime.h>
#include <hip/hip_bf16.h>
#include <stdint.h>

typedef __bf16 bf16x4v __attribute__((ext_vector_type(4)));
typedef __bf16 bf16x8  __attribute__((ext_vector_type(8)));
typedef float  f32x4   __attribute__((ext_vector_type(4)));
typedef float  f32x2   __attribute__((ext_vector_type(2)));
typedef float  f32x16  __attribute__((ext_vector_type(16)));

#define KC 200
#define KB 8                       // k per block (32B write chunks: L2-merge ideal)
#define CBASE (-58.8120661251f)    // -0.5 * 64 * log(2*pi)

// ws layout:
//   Ltf : bf16 [200][8][512]  fragment-order: inst=(et*4+ki), lane, j
//         value = prec^T[k][e=et*32+(lane&31)][d=16ki+8*(lane>>5)+j]      0 .. 1638400
//   muL : f32  [200][64]                                            1638400 .. 1689600
//   ckh : f32  [2][200] (partial logdets)                           1689600 .. 1691200
//   xb  : bf16 [16384][64] (x converted)                            1691200 .. 3788352

// ---------------- prepass: 400 blocks (k, e-half) + 256 blocks x->bf16 ----------------
__global__ __launch_bounds__(256) void prep(const float* __restrict__ prec,
                                            const float* __restrict__ means,
                                            const float* __restrict__ x,
                                            __bf16* __restrict__ Ltf,
                                            float* __restrict__ muL,
                                            float* __restrict__ ckh,
                                            __bf16* __restrict__ xb) {
    const int tid = threadIdx.x;
    if (blockIdx.x >= 400) {        // ---- x -> bf16 (1M elems over 256 blocks) ----
        const size_t base = (size_t)(blockIdx.x - 400) * 4096;
        #pragma unroll
        for (int r = 0; r < 4; ++r) {
            size_t idx = base + r * 1024 + tid * 4;
            float4 v = *(const float4*)(x + idx);
            bf16x4v o = {(__bf16)v.x, (__bf16)v.y, (__bf16)v.z, (__bf16)v.w};
            *(bf16x4v*)(xb + idx) = o;
        }
        return;
    }
    __shared__ float sP[64][40];   // [d][e-in-half], padded
    __shared__ float sM[64];
    const int k = blockIdx.x >> 1, h = blockIdx.x & 1;
    const float* pk = prec + (size_t)k * 4096 + h * 32;
    #pragma unroll
    for (int it = 0; it < 2; ++it) {
        int f4 = tid + it * 256;            // 512 float4 = 64 rows x 8
        int d = f4 >> 3, c = (f4 & 7) * 4;
        float4 v = *(const float4*)(pk + (size_t)d * 64 + c);
        *(float4*)&sP[d][c] = v;
    }
    if (tid < 16) *(float4*)&sM[tid * 4] = ((const float4*)(means + (size_t)k * 64))[tid];
    __syncthreads();
    {   // fragment-order write: inst=(h*4+ki), lane, j -> sP[16ki+8hp+j][l31]
        int lane = tid & 63, ki = tid >> 6;
        int hp = lane >> 5, l31 = lane & 31;
        bf16x8 o;
        #pragma unroll
        for (int j = 0; j < 8; ++j) o[j] = (__bf16)sP[16 * ki + 8 * hp + j][l31];
        *(bf16x8*)(Ltf + (size_t)k * 4096 + (h * 4 + ki) * 512 + lane * 8) = o;
    }
    if (tid < 32) {
        int e = tid;
        float m = 0.f;
        #pragma unroll 8
        for (int d = 0; d < 64; ++d) m = fmaf(sM[d], sP[d][e], m);
        muL[k * 64 + h * 32 + e] = m;
        float l = __logf(sP[h * 32 + e][e]);   // diag entry (h*32+e, h*32+e)
        #pragma unroll
        for (int mm = 16; mm >= 1; mm >>= 1) l += __shfl_xor(l, mm, 64);
        if (e == 0) ckh[h * KC + k] = l;
    }
}

// ---------------- main: wave<->k decomposition, 128-row blocks ----------------
// acc[e][row] = Lt_k . x^T - muL (C operand = -muL). A = Lt (regs, from global, issued
// pre-barrier), B = x rows (LDS, staged once, shared by all 4 waves). 32x32x16 layouts
// (R6/R9/R10-validated): A[m=lane&31][k=8*(lane>>5)+j], B[k][n=lane&31],
// C/D col=lane&31, row=(reg&3)+8*(reg>>2)+4*(lane>>5).
// R12: (1) hp-half reduction DEFERRED to flush (no __shfl in hot loop: both halves
// store partials to sOutT[k][hp][row]); (2) rt iteration rotated by wave to de-phase
// the four waves' MFMA/epilogue bursts.
#define GLL16(gp_, lp_) \
    __builtin_amdgcn_global_load_lds((__attribute__((address_space(1))) const void*)(gp_), \
                                     (__attribute__((address_space(3))) void*)(lp_), 16, 0, 0)

__global__ __launch_bounds__(256, 4) void gmm_main(const __bf16* __restrict__ xb,
                                                   const __bf16* __restrict__ Ltf,
                                                   const float* __restrict__ muL,
                                                   const float* __restrict__ ckh,
                                                   float* __restrict__ out) {
    __shared__ __align__(16) __bf16 sX[128 * 64];       // 16 KB, seg-swizzled rows
    __shared__ __align__(16) float  sOutT[KB][2][128];  // 8 KB: [k][hp][row] partials
    __shared__ float sCk[KB];

    const int tid  = threadIdx.x;
    const int wave = tid >> 6, lane = tid & 63;
    const int hp   = lane >> 5;
    const int l31  = lane & 31;
    const int r8   = lane >> 3, s8 = lane & 7;
    const int row0 = blockIdx.x * 128;
    const int k0   = blockIdx.y * KB;
    char* sXc = (char*)sX;

    // --- stage x tile: 16 GLL16 (1 KB each), swizzle in source addresses ---
    #pragma unroll
    for (int i = 0; i < 4; ++i) {
        int t = wave * 4 + i;                 // 8-row group, t = 0..15
        GLL16(xb + (size_t)(row0 + t * 8 + r8) * 64 + (s8 ^ r8) * 8, sXc + t * 1024);
    }

    // --- pre-barrier prefetch: first k's fragments + mu + ck (in flight across barrier) ---
    const int kA = k0 + wave * 2;
    bf16x8 lf[2][4];
    #pragma unroll
    for (int et = 0; et < 2; ++et)
        #pragma unroll
        for (int ki = 0; ki < 4; ++ki)
            lf[et][ki] = *(const bf16x8*)(Ltf + (size_t)kA * 4096 + (et * 4 + ki) * 512 + lane * 8);
    f32x16 c0[2];
    #pragma unroll
    for (int et = 0; et < 2; ++et)
        #pragma unroll
        for (int q2 = 0; q2 < 4; ++q2) {
            f32x4 m = *(const f32x4*)(muL + (size_t)kA * 64 + et * 32 + 8 * q2 + 4 * hp);
            c0[et][4 * q2 + 0] = -m[0]; c0[et][4 * q2 + 1] = -m[1];
            c0[et][4 * q2 + 2] = -m[2]; c0[et][4 * q2 + 3] = -m[3];
        }
    if (lane == 0) sCk[wave * 2] = ckh[kA] + ckh[KC + kA] + CBASE;

    __syncthreads();

    #pragma unroll
    for (int ks = 0; ks < 2; ++ks) {
        const int kl = wave * 2 + ks;
        if (ks == 1) {   // reload fragments for second k (L2-hot)
            const int kB_ = k0 + wave * 2 + 1;
            #pragma unroll
            for (int et = 0; et < 2; ++et)
                #pragma unroll
                for (int ki = 0; ki < 4; ++ki)
                    lf[et][ki] = *(const bf16x8*)(Ltf + (size_t)kB_ * 4096 + (et * 4 + ki) * 512 + lane * 8);
            #pragma unroll
            for (int et = 0; et < 2; ++et)
                #pragma unroll
                for (int q2 = 0; q2 < 4; ++q2) {
                    f32x4 m = *(const f32x4*)(muL + (size_t)kB_ * 64 + et * 32 + 8 * q2 + 4 * hp);
                    c0[et][4 * q2 + 0] = -m[0]; c0[et][4 * q2 + 1] = -m[1];
                    c0[et][4 * q2 + 2] = -m[2]; c0[et][4 * q2 + 3] = -m[3];
                }
            if (lane == 0) sCk[kl] = ckh[kB_] + ckh[KC + kB_] + CBASE;
        }

        #pragma unroll
        for (int r4 = 0; r4 < 4; ++r4) {      // de-phased: each wave starts at its own rt
            const int rt = (r4 + wave) & 3;
            bf16x8 xf[4];
            #pragma unroll
            for (int ki = 0; ki < 4; ++ki)
                xf[ki] = *(const bf16x8*)(sXc + (rt * 32 + l31) * 128
                                          + (((2 * ki + hp) ^ (l31 & 7)) << 4));
            f32x16 a0 = __builtin_amdgcn_mfma_f32_32x32x16_bf16(lf[0][0], xf[0], c0[0], 0, 0, 0);
            f32x16 a1 = __builtin_amdgcn_mfma_f32_32x32x16_bf16(lf[1][0], xf[0], c0[1], 0, 0, 0);
            #pragma unroll
            for (int ki = 1; ki < 4; ++ki) {
                a0 = __builtin_amdgcn_mfma_f32_32x32x16_bf16(lf[0][ki], xf[ki], a0, 0, 0, 0);
                a1 = __builtin_amdgcn_mfma_f32_32x32x16_bf16(lf[1][ki], xf[ki], a1, 0, 0, 0);
            }
            // --- tree-reduced squared-sum: 4 independent pk_fma chains of depth 4 ---
            f32x2 q0 = {0.f, 0.f}, q1 = {0.f, 0.f}, q2 = {0.f, 0.f}, q3 = {0.f, 0.f};
            #pragma unroll
            for (int i = 0; i < 4; ++i) {
                f32x2 u0 = {a0[2 * i],     a0[2 * i + 1]};
                f32x2 u1 = {a0[2 * i + 8], a0[2 * i + 9]};
                f32x2 v0 = {a1[2 * i],     a1[2 * i + 1]};
                f32x2 v1 = {a1[2 * i + 8], a1[2 * i + 9]};
                q0 += u0 * u0;   // v_pk_fma_f32, 4 independent accumulators
                q1 += u1 * u1;
                q2 += v0 * v0;
                q3 += v1 * v1;
            }
            f32x2 s01 = q0 + q1;
            f32x2 s23 = q2 + q3;
            f32x2 st  = s01 + s23;
            // both hp-halves store their partial; combined in flush (no shuffle here)
            sOutT[kl][hp][rt * 32 + l31] = st[0] + st[1];
        }
    }
    __syncthreads();

    // --- flush: thread t -> row t/2, k-half t&1: combine halves + scale + float4 store ---
    {
        const int r = tid >> 1, h = tid & 1;
        f32x4 a;
        #pragma unroll
        for (int j = 0; j < 4; ++j) {
            int k = h * 4 + j;
            float s = sOutT[k][0][r] + sOutT[k][1][r];
            a[j] = fmaf(-0.5f, s, sCk[k]);
        }
        *(f32x4*)(out + (size_t)(row0 + r) * KC + k0 + h * 4) = a;
    }
}

extern "C" void kernel_launch(void* const* d_in, const int* in_sizes, int n_in,
                              void* d_out, int out_size, void* d_ws, size_t ws_size,
                              hipStream_t stream) {
    const float* x     = (const float*)d_in[0];   // [16384, 64]
    const float* means = (const float*)d_in[1];   // [200, 64]
    const float* prec  = (const float*)d_in[2];   // [200, 64, 64]
    float* out = (float*)d_out;                   // [16384, 200]

    __bf16* Ltf = (__bf16*)d_ws;
    float*  muL = (float*)((char*)d_ws + 1638400);
    float*  ckh = (float*)((char*)d_ws + 1689600);
    __bf16* xb  = (__bf16*)((char*)d_ws + 1691200);

    prep<<<656, 256, 0, stream>>>(prec, means, x, Ltf, muL, ckh, xb);
    gmm_main<<<dim3(128, KC / KB), 256, 0, stream>>>(xb, Ltf, muL, ckh, out);
}